// Round 6
// baseline (491.373 us; speedup 1.0000x reference)
//
#include <hip/hip_runtime.h>
#include <math.h>

// Problem constants
#define Kn    30
#define Hn    128
#define NB    2048          // nodes per batch
#define YS    136           // row stride (128 + 8 pad): 17 16B-groups (odd) -> conflict-free b128

// ws layout: bf16 weights, then fp32 scratch
#define OFF_W1    0
#define OFF_W2    49152
#define OFF_W3    65536
#define OFF_W11   81920
#define OFF_W12   131072
#define OFF_W13   147456
#define OFF_WIN   163840
#define OFF_WOUT  229376
#define W_TOTAL   294912
// fp32 scratch offsets (in floats, relative to end of weight region)
#define WS_ZM     524288    // zm [8192] fp32 (z bf16 occupies [0,524288) floats)
#define WS_SS     1048576   // self-term: s1self, then (aliased) s11self
#define WS_SN     2097152   // nbr-term:  s1nbr,  then (aliased) s11nbr

typedef __attribute__((ext_vector_type(8)))  short bh8;
typedef __attribute__((ext_vector_type(4)))  short bh4;
typedef __attribute__((ext_vector_type(16))) float fx16;

__device__ __forceinline__ unsigned short f2bf(float f) {
    unsigned int u = __float_as_uint(f);
    u += 0x7fffu + ((u >> 16) & 1u);        // RNE
    return (unsigned short)(u >> 16);
}
__device__ __forceinline__ float bf2f(unsigned short h) {
    return __uint_as_float(((unsigned int)h) << 16);
}
// HW packed f32x2 -> bf16x2 (RNE), gfx950 (1 VALU inst for 2 elements)
__device__ __forceinline__ unsigned int cvt_pk(float lo, float hi) {
    unsigned int r;
    asm("v_cvt_pk_bf16_f32 %0, %1, %2" : "=v"(r) : "v"(lo), "v"(hi));
    return r;
}
// tanh-form GELU, exp2-folded + fast rcp: x * rcp(1 + 2^(x*(c0 + c1 x^2)))
// |err vs erf-GELU| <~1e-3 (same approx family as before; passed via R2 hV path)
__device__ __forceinline__ float gelu_f(float x) {
    float x2 = x * x;
    float p  = fmaf(x2, -0.10294415f, -2.30218409f);
    float e  = exp2f(x * p);
    return x * __builtin_amdgcn_rcpf(1.0f + e);
}
__device__ __forceinline__ fx16 mfma_bf16(bh8 a, bh8 b, fx16 c) {
    return __builtin_amdgcn_mfma_f32_32x32x16_bf16(a, b, c, 0, 0, 0);
}
__device__ __forceinline__ void st_bf4(unsigned short* dst, float4 v) {
    uint2 t;
    t.x = cvt_pk(v.x, v.y);
    t.y = cvt_pk(v.z, v.w);
    *(uint2*)dst = t;                        // ds_write_b64
}

// Fully-unrolled K-loop, single B n-tile (8-wave mapping: 1 tile/wave).
template<int KS>
__device__ __forceinline__ void gemm_one(const unsigned short* __restrict__ aBase,
                                         const unsigned short* __restrict__ b0,
                                         fx16& acc0) {
    #pragma unroll
    for (int ks = 0; ks < KS; ks++) {
        bh8 a = *(const bh8*)(aBase + ks * 16);
        acc0 = mfma_bf16(a, *(const bh8*)(b0 + ks * 16), acc0);
    }
}

// C-layout (verified m74/m101): col = lane&31, row = (reg&3)+8*(reg>>2)+4*(lane>>5)
// Pairs (r, r+1) always land on adjacent rows (row1 = row0+1), so each pair is
// one cvt_pk + lo/hi b16 stores. Kn=30 is even -> self-term boundary never
// straddles a pair, but st is computed per element anyway.
__device__ __forceinline__ void epi_gelu_sg(const fx16& ac, int col, int rowBase,
                                            float bias, const float* __restrict__ sSelf,
                                            const float* __restrict__ nbrCol,
                                            const int* __restrict__ sIdx,
                                            unsigned short* __restrict__ dst, int lane) {
    int ro = rowBase + 4 * (lane >> 5);
    #pragma unroll
    for (int r = 0; r < 16; r += 2) {
        int row0 = ro + (r & 3) + 8 * (r >> 2);
        int row1 = row0 + 1;
        float st0 = sSelf[((row0 >= Kn) ? 128 : 0) + col];
        float st1 = sSelf[((row1 >= Kn) ? 128 : 0) + col];
        float pn0 = nbrCol[(size_t)sIdx[row0] * Hn];
        float pn1 = nbrCol[(size_t)sIdx[row1] * Hn];
        float e0 = gelu_f(ac[r]     + bias + st0 + pn0);
        float e1 = gelu_f(ac[r + 1] + bias + st1 + pn1);
        unsigned int u = cvt_pk(e0, e1);
        dst[row0 * YS + col] = (unsigned short)u;
        dst[row1 * YS + col] = (unsigned short)(u >> 16);
    }
}
__device__ __forceinline__ void epi_gelu(const fx16& ac, int col, int rowBase,
                                         float bias, unsigned short* __restrict__ dst,
                                         int lane) {
    int ro = rowBase + 4 * (lane >> 5);
    #pragma unroll
    for (int r = 0; r < 16; r += 2) {
        int row0 = ro + (r & 3) + 8 * (r >> 2);
        int row1 = row0 + 1;
        float e0 = gelu_f(ac[r]     + bias);
        float e1 = gelu_f(ac[r + 1] + bias);
        unsigned int u = cvt_pk(e0, e1);
        dst[row0 * YS + col] = (unsigned short)u;
        dst[row1 * YS + col] = (unsigned short)(u >> 16);
    }
}
__device__ __forceinline__ void epi_plain(const fx16& ac, int col, int rowBase,
                                          float bias, unsigned short* __restrict__ dst,
                                          int lane) {
    int ro = rowBase + 4 * (lane >> 5);
    #pragma unroll
    for (int r = 0; r < 16; r += 2) {
        int row0 = ro + (r & 3) + 8 * (r >> 2);
        int row1 = row0 + 1;
        unsigned int u = cvt_pk(ac[r] + bias, ac[r + 1] + bias);
        dst[row0 * YS + col] = (unsigned short)u;
        dst[row1 * YS + col] = (unsigned short)(u >> 16);
    }
}

// ---------------------------------------------------------------------------
// prep: fp32 -> bf16 weights into workspace
// ---------------------------------------------------------------------------
__global__ __launch_bounds__(256) void prep_weights(
    const float* __restrict__ W1, const float* __restrict__ W2,
    const float* __restrict__ W3, const float* __restrict__ W11,
    const float* __restrict__ W12, const float* __restrict__ W13,
    const float* __restrict__ Win, const float* __restrict__ Wout,
    unsigned short* __restrict__ wsbf) {
    int i = blockIdx.x * 256 + threadIdx.x;
    if (i >= W_TOTAL) return;
    float v;
    if      (i < OFF_W2)   v = W1[i - OFF_W1];
    else if (i < OFF_W3)   v = W2[i - OFF_W2];
    else if (i < OFF_W11)  v = W3[i - OFF_W3];
    else if (i < OFF_W12)  v = W11[i - OFF_W11];
    else if (i < OFF_W13)  v = W12[i - OFF_W12];
    else if (i < OFF_WIN)  v = W13[i - OFF_W13];
    else if (i < OFF_WOUT) v = Win[i - OFF_WIN];
    else                   v = Wout[i - OFF_WOUT];
    wsbf[i] = f2bf(v);
}

// ---------------------------------------------------------------------------
// self+nbr terms for node GEMM1:
//   s1s[p] = h_V[p] @ W1[:,0:128]^T      (self columns)
//   s1n[p] = h_V[p] @ W1[:,256:384]^T    (neighbor columns; gathered later)
// ---------------------------------------------------------------------------
__global__ __launch_bounds__(256) void self_gemm(
    const float* __restrict__ hv, const unsigned short* __restrict__ wsbf,
    float* __restrict__ s1s, float* __restrict__ s1n) {
    __shared__ __align__(16) unsigned short sA[32 * YS];
    const int tid = threadIdx.x;
    const int p0 = blockIdx.x * 32;
    const unsigned short* W1bf = wsbf + OFF_W1;
    for (int i = tid; i < 1024; i += 256) {
        int r = i >> 5, c4 = (i & 31) << 2;
        float4 v = *(const float4*)(hv + (size_t)(p0 + r) * Hn + c4);
        st_bf4(sA + r * YS + c4, v);
    }
    __syncthreads();
    const int wid = tid >> 6, lane = tid & 63;
    const int lane31 = lane & 31, lk = (lane >> 5) << 3;
    fx16 accS = {}, accN = {};
    const unsigned short* a   = sA + lane31 * YS + lk;
    const unsigned short* bwS = W1bf + (size_t)(32 * wid + lane31) * 384 + lk;        // cols 0..127
    const unsigned short* bwN = bwS + 256;                                            // cols 256..383
    #pragma unroll
    for (int ks = 0; ks < 8; ks++) {
        bh8 av = *(const bh8*)(a + ks * 16);
        accS = mfma_bf16(av, *(const bh8*)(bwS + ks * 16), accS);
        accN = mfma_bf16(av, *(const bh8*)(bwN + ks * 16), accN);
    }
    int col = 32 * wid + lane31;
    #pragma unroll
    for (int r = 0; r < 16; r++) {
        int row = (r & 3) + 8 * (r >> 2) + 4 * (lane >> 5);
        s1s[(size_t)(p0 + row) * Hn + col] = accS[r];
        s1n[(size_t)(p0 + row) * Hn + col] = accN[r];
    }
}

// ---------------------------------------------------------------------------
// Kernel A: node message MLP (8 waves, 512 thr). Each wave: one 32-row x
// 32-col output tile (mt=wid&1 row-half, ct=wid>>1 col-quarter).
// z[node] = sum_k mask_k * gelu(Y2_k); dh finished as z@W3^T in kernel B.
// Neighbor term gathered directly in GEMM1 epilogue (no prefetch regs).
// ---------------------------------------------------------------------------
__global__ __launch_bounds__(512, 8) void node_msg_mfma(
    const float* __restrict__ h_E, const int* __restrict__ E_idx,
    const float* __restrict__ mask_attend,
    const unsigned short* __restrict__ wsbf,
    const float* __restrict__ s1s, const float* __restrict__ s1n,
    const float* __restrict__ W1_b, const float* __restrict__ W2_b,
    unsigned short* __restrict__ zbf, float* __restrict__ zm) {
    __shared__ __align__(16) unsigned short sX[64 * YS]; // h_E; fp32 scratch after GEMM1
    __shared__ __align__(16) unsigned short sY[64 * YS];
    __shared__ float sS1[256];
    __shared__ float sMask[64];
    __shared__ int   sIdx[64];

    const int tid = threadIdx.x;
    const int p0 = blockIdx.x * 2;
    const int bB = p0 >> 11;
    const unsigned short* W1bf = wsbf + OFF_W1;
    const unsigned short* W2bf = wsbf + OFF_W2;

    // ---- staging: h_E only ----
    for (int i = tid; i < 1920; i += 512) {
        int r = i >> 5, c4 = (i & 31) << 2;
        float4 v = *(const float4*)(h_E + ((size_t)(p0 * Kn + r)) * Hn + c4);
        st_bf4(sX + r * YS + c4, v);
    }
    if (tid < 272)                                   // zero pad rows 60..63
        ((unsigned int*)(sX + 60 * YS))[tid] = 0;
    if (tid < 64) {
        int g = tid >> 5, c4 = (tid & 31) << 2;
        *(float4*)(sS1 + g * 128 + c4) = *(const float4*)(s1s + (size_t)(p0 + g) * Hn + c4);
    }
    if (tid < 60) sMask[tid] = mask_attend[p0 * Kn + tid];
    if (tid < 64) sIdx[tid] = (tid < 60) ? E_idx[p0 * Kn + tid] : 0;
    __syncthreads();

    const int wid = tid >> 6, lane = tid & 63;
    const int mt = wid & 1, ct = wid >> 1;
    const int lane31 = lane & 31, lk = (lane >> 5) << 3;
    const int rowBase = 32 * mt;
    const fx16 zv = {};
    const int col = 32 * ct + lane31;

    // ---- GEMM1: X[64,128] @ W1[:,128:256]^T + s1s + s1n(gathered) + b -> GELU -> Y ----
    fx16 acc = zv;
    gemm_one<8>(sX + (rowBase + lane31) * YS + lk,
                W1bf + (size_t)col * 384 + 128 + lk, acc);
    epi_gelu_sg(acc, col, rowBase, W1_b[col], sS1,
                s1n + (size_t)bB * NB * Hn + col, sIdx, sY, lane);
    __syncthreads();

    // ---- GEMM2 + fused gelu + masked k-reduction (no GEMM3) ----
    acc = zv;
    gemm_one<8>(sY + (rowBase + lane31) * YS + lk,
                W2bf + (size_t)col * 128 + lk, acc);
    float* fbuf = (float*)sX;                        // sX dead after GEMM1
    {
        float bias = W2_b[col];
        float sA0 = 0.f, sA1 = 0.f;
        #pragma unroll
        for (int r = 0; r < 16; r++) {
            int row = rowBase + (r & 3) + 8 * (r >> 2) + 4 * (lane >> 5);
            if (row < 60) {
                float v = gelu_f(acc[r] + bias) * sMask[row];
                if (row < Kn) sA0 += v; else sA1 += v;
            }
        }
        sA0 += __shfl_down(sA0, 32);
        sA1 += __shfl_down(sA1, 32);
        if (lane < 32) { fbuf[mt * 256 + col] = sA0; fbuf[mt * 256 + 128 + col] = sA1; }
    }
    __syncthreads();

    // ---- combine cross-wave partials, write z (bf16, pre-scaled by 1/30) ----
    if (tid < 256) {
        int g = tid >> 7, c = tid & 127;
        float zval = (fbuf[g * 128 + c] + fbuf[256 + g * 128 + c]) * (1.0f / 30.0f);
        zbf[(size_t)(p0 + g) * Hn + c] = f2bf(zval);
    }
    if (tid < 2) {
        float s = 0.f;
        #pragma unroll
        for (int k = 0; k < 30; k++) s += sMask[tid * 30 + k];
        zm[p0 + tid] = s * (1.0f / 30.0f);
    }
}

// ---------------------------------------------------------------------------
// Kernel B: dh = z@W3^T + zm*b3; LN1 (+h_V residual); FFN; LN2 + mask_V;
// then s11s/s11n = hV_out @ W11{self,nbr}^T. hmid never touches HBM.
// ---------------------------------------------------------------------------
__global__ __launch_bounds__(256) void node_fin_ffn(
    const unsigned short* __restrict__ zbf, const float* __restrict__ zm,
    const float* __restrict__ h_V, const float* __restrict__ mask_V,
    const unsigned short* __restrict__ wsbf,
    const float* __restrict__ W3_b, const float* __restrict__ Win_b,
    const float* __restrict__ Wout_b,
    const float* __restrict__ g1v, const float* __restrict__ b1v,
    const float* __restrict__ g2v, const float* __restrict__ b2v,
    float* __restrict__ hV_out, float* __restrict__ s11s, float* __restrict__ s11n) {
    __shared__ __align__(16) unsigned short sA[32 * YS];  // z bf16, then hmid bf16
    __shared__ __align__(16) unsigned short sH[32 * YS];  // hidden chunk bf16
    __shared__ __align__(16) float sO[32 * 132];          // dh fp32, then FFN-out fp32
    __shared__ __align__(16) float sM[32 * 132];          // hmid fp32
    __shared__ __align__(16) unsigned short sV[32 * YS];  // hV_out bf16 for s11
    __shared__ float sZm[32];

    const int tid = threadIdx.x;
    const int p0 = blockIdx.x * 32;
    const unsigned short* W3bf   = wsbf + OFF_W3;
    const unsigned short* Winbf  = wsbf + OFF_WIN;
    const unsigned short* Woutbf = wsbf + OFF_WOUT;
    const unsigned short* W11bf  = wsbf + OFF_W11;

    for (int i = tid; i < 512; i += 256) {
        int r = i >> 4, c8 = (i & 15) << 3;
        *(bh8*)(sA + r * YS + c8) = *(const bh8*)(zbf + (size_t)(p0 + r) * Hn + c8);
    }
    if (tid < 32) sZm[tid] = zm[p0 + tid];
    __syncthreads();

    const int wid = tid >> 6, lane = tid & 63;
    const int lane31 = lane & 31, lk = (lane >> 5) << 3;
    const fx16 zv = {};

    // ---- dh GEMM: z[32,128] @ W3^T ----
    {
        fx16 acc = zv;
        const unsigned short* a  = sA + lane31 * YS + lk;
        const unsigned short* bw = W3bf + (size_t)(32 * wid + lane31) * 128 + lk;
        #pragma unroll
        for (int ks = 0; ks < 8; ks++)
            acc = mfma_bf16(*(const bh8*)(a + ks * 16), *(const bh8*)(bw + ks * 16), acc);
        int col = 32 * wid + lane31;
        float bias = W3_b[col];
        #pragma unroll
        for (int r = 0; r < 16; r++) {
            int row = (r & 3) + 8 * (r >> 2) + 4 * (lane >> 5);
            sO[row * 132 + col] = acc[r] + sZm[row] * bias;
        }
    }
    __syncthreads();

    // ---- LN1: x = h_V + dh -> hmid (sM fp32 + sA bf16) ----
    for (int r = wid; r < 32; r += 4) {
        float x0 = sO[r * 132 + lane]      + h_V[(size_t)(p0 + r) * Hn + lane];
        float x1 = sO[r * 132 + 64 + lane] + h_V[(size_t)(p0 + r) * Hn + 64 + lane];
        float s = x0 + x1, q = x0 * x0 + x1 * x1;
        #pragma unroll
        for (int off = 32; off; off >>= 1) { s += __shfl_down(s, off); q += __shfl_down(q, off); }
        s = __shfl(s, 0); q = __shfl(q, 0);
        float mean = s * 0.0078125f;
        float rstd = rsqrtf(q * 0.0078125f - mean * mean + 1e-5f);
        float m0 = (x0 - mean) * rstd * g1v[lane]      + b1v[lane];
        float m1 = (x1 - mean) * rstd * g1v[lane + 64] + b1v[lane + 64];
        sM[r * 132 + lane]      = m0;
        sM[r * 132 + 64 + lane] = m1;
        sA[r * YS + lane]      = f2bf(m0);
        sA[r * YS + 64 + lane] = f2bf(m1);
    }
    __syncthreads();

    // ---- FFN ----
    fx16 accO = zv;
    for (int c = 0; c < 4; c++) {
        int hcol = 128 * c + 32 * wid + lane31;
        fx16 t = zv;
        {
            const unsigned short* a  = sA + lane31 * YS + lk;
            const unsigned short* bw = Winbf + (size_t)hcol * 128 + lk;
            #pragma unroll
            for (int ks = 0; ks < 8; ks++)
                t = mfma_bf16(*(const bh8*)(a + ks * 16), *(const bh8*)(bw + ks * 16), t);
        }
        float bias = Win_b[hcol];
        int colL = 32 * wid + lane31;
        #pragma unroll
        for (int r = 0; r < 16; r++) {
            int row = (r & 3) + 8 * (r >> 2) + 4 * (lane >> 5);
            sH[row * YS + colL] = f2bf(gelu_f(t[r] + bias));
        }
        __syncthreads();
        {
            const unsigned short* a  = sH + lane31 * YS + lk;
            const unsigned short* bw = Woutbf + (size_t)(32 * wid + lane31) * 512 + 128 * c + lk;
            #pragma unroll
            for (int ks = 0; ks < 8; ks++)
                accO = mfma_bf16(*(const bh8*)(a + ks * 16), *(const bh8*)(bw + ks * 16), accO);
        }
        __syncthreads();
    }
    {
        int col = 32 * wid + lane31;
        float bias = Wout_b[col];
        #pragma unroll
        for (int r = 0; r < 16; r++) {
            int row = (r & 3) + 8 * (r >> 2) + 4 * (lane >> 5);
            sO[row * 132 + col] = accO[r] + bias;
        }
    }
    __syncthreads();

    // ---- LN2 + mask_V -> hV_out, sV ----
    for (int r = wid; r < 32; r += 4) {
        float x0 = sO[r * 132 + lane]      + sM[r * 132 + lane];
        float x1 = sO[r * 132 + 64 + lane] + sM[r * 132 + 64 + lane];
        float s = x0 + x1, q = x0 * x0 + x1 * x1;
        #pragma unroll
        for (int off = 32; off; off >>= 1) { s += __shfl_down(s, off); q += __shfl_down(q, off); }
        s = __shfl(s, 0); q = __shfl(q, 0);
        float mean = s * 0.0078125f;
        float rstd = rsqrtf(q * 0.0078125f - mean * mean + 1e-5f);
        float mv = mask_V[p0 + r];
        float y0 = ((x0 - mean) * rstd * g2v[lane]      + b2v[lane])      * mv;
        float y1 = ((x1 - mean) * rstd * g2v[lane + 64] + b2v[lane + 64]) * mv;
        hV_out[(size_t)(p0 + r) * Hn + lane]      = y0;
        hV_out[(size_t)(p0 + r) * Hn + 64 + lane] = y1;
        sV[r * YS + lane]      = f2bf(y0);
        sV[r * YS + 64 + lane] = f2bf(y1);
    }
    __syncthreads();

    // ---- s11s/s11n = hV_out @ W11{self,nbr}^T ----
    {
        int col = 32 * wid + lane31;
        fx16 accS = zv, accN = zv;
        const unsigned short* a   = sV + lane31 * YS + lk;
        const unsigned short* bwS = W11bf + (size_t)col * 384 + lk;        // self cols 0..127
        const unsigned short* bwN = W11bf + (size_t)col * 384 + 256 + lk;  // nbr  cols 256..383
        #pragma unroll
        for (int ks = 0; ks < 8; ks++) {
            bh8 av = *(const bh8*)(a + ks * 16);
            accS = mfma_bf16(av, *(const bh8*)(bwS + ks * 16), accS);
            accN = mfma_bf16(av, *(const bh8*)(bwN + ks * 16), accN);
        }
        #pragma unroll
        for (int r = 0; r < 16; r++) {
            int row = (r & 3) + 8 * (r >> 2) + 4 * (lane >> 5);
            s11s[(size_t)(p0 + row) * Hn + col] = accS[r];
            s11n[(size_t)(p0 + row) * Hn + col] = accN[r];
        }
    }
}

// ---------------------------------------------------------------------------
// Kernel C: edge update (8 waves, 512 thr) — R3-verified barrier structure;
// LN tail parallelized 8-lanes-per-row (single pass, vector LDS reads).
// ---------------------------------------------------------------------------
__global__ __launch_bounds__(512, 8) void edge_update_mfma(
    const float* __restrict__ h_E, const int* __restrict__ E_idx,
    const unsigned short* __restrict__ wsbf,
    const float* __restrict__ s11s, const float* __restrict__ s11n,
    const float* __restrict__ W11_b, const float* __restrict__ W12_b,
    const float* __restrict__ W13_b,
    const float* __restrict__ g3v, const float* __restrict__ b3v,
    float* __restrict__ hE_out) {
    __shared__ __align__(16) unsigned short sX[64 * YS]; // h_E, live to end (residual)
    __shared__ __align__(16) unsigned short sY[64 * YS];
    __shared__ float sS11[256];
    __shared__ int   sIdx[64];

    const int tid = threadIdx.x;
    const int p0 = blockIdx.x * 2;
    const int bB = p0 >> 11;
    const unsigned short* W11bf = wsbf + OFF_W11;
    const unsigned short* W12bf = wsbf + OFF_W12;
    const unsigned short* W13bf = wsbf + OFF_W13;

    for (int i = tid; i < 1920; i += 512) {
        int r = i >> 5, c4 = (i & 31) << 2;
        float4 v = *(const float4*)(h_E + ((size_t)(p0 * Kn + r)) * Hn + c4);
        st_bf4(sX + r * YS + c4, v);
    }
    if (tid < 272)
        ((unsigned int*)(sX + 60 * YS))[tid] = 0;
    if (tid < 64) {
        int g = tid >> 5, c4 = (tid & 31) << 2;
        *(float4*)(sS11 + g * 128 + c4) = *(const float4*)(s11s + (size_t)(p0 + g) * Hn + c4);
    }
    if (tid < 64) sIdx[tid] = (tid < 60) ? E_idx[p0 * Kn + tid] : 0;
    __syncthreads();

    const int wid = tid >> 6, lane = tid & 63;
    const int mt = wid & 1, ct = wid >> 1;
    const int lane31 = lane & 31, lk = (lane >> 5) << 3;
    const int rowBase = 32 * mt;
    const fx16 zv = {};
    const int col = 32 * ct + lane31;

    fx16 acc = zv;
    gemm_one<8>(sX + (rowBase + lane31) * YS + lk,
                W11bf + (size_t)col * 384 + 128 + lk, acc);
    epi_gelu_sg(acc, col, rowBase, W11_b[col], sS11,
                s11n + (size_t)bB * NB * Hn + col, sIdx, sY, lane);
    __syncthreads();

    acc = zv;
    gemm_one<8>(sY + (rowBase + lane31) * YS + lk,
                W12bf + (size_t)col * 128 + lk, acc);
    __syncthreads();
    epi_gelu(acc, col, rowBase, W12_b[col], sY, lane);
    __syncthreads();

    acc = zv;
    gemm_one<8>(sY + (rowBase + lane31) * YS + lk,
                W13bf + (size_t)col * 128 + lk, acc);
    __syncthreads();
    epi_plain(acc, col, rowBase, W13_b[col], sY, lane);
    __syncthreads();

    // per-edge-row LN over E=128: 8 lanes/row x 16 cols, single pass
    // (512 threads -> 64 row-groups, rows 0..59 active)
    {
        int r  = tid >> 3;
        if (r < 60) {
            int cb = (tid & 7) * 16;
            bh8 vx0 = *(const bh8*)(sX + r * YS + cb);
            bh8 vx1 = *(const bh8*)(sX + r * YS + cb + 8);
            bh8 vy0 = *(const bh8*)(sY + r * YS + cb);
            bh8 vy1 = *(const bh8*)(sY + r * YS + cb + 8);
            float xs[16];
            float s = 0.f, q = 0.f;
            #pragma unroll
            for (int j = 0; j < 8; j++) {
                float x = bf2f((unsigned short)vx0[j]) + bf2f((unsigned short)vy0[j]);
                xs[j] = x; s += x; q += x * x;
            }
            #pragma unroll
            for (int j = 0; j < 8; j++) {
                float x = bf2f((unsigned short)vx1[j]) + bf2f((unsigned short)vy1[j]);
                xs[8 + j] = x; s += x; q += x * x;
            }
            s += __shfl_xor(s, 1); q += __shfl_xor(q, 1);
            s += __shfl_xor(s, 2); q += __shfl_xor(q, 2);
            s += __shfl_xor(s, 4); q += __shfl_xor(q, 4);
            float mean = s * 0.0078125f;
            float rstd = rsqrtf(q * 0.0078125f - mean * mean + 1e-5f);
            float* op = hE_out + ((size_t)(p0 * Kn + r)) * Hn + cb;
            const float* gp = g3v + cb;
            const float* bp = b3v + cb;
            #pragma unroll
            for (int j4 = 0; j4 < 4; j4++) {
                float4 o;
                o.x = (xs[j4 * 4 + 0] - mean) * rstd * gp[j4 * 4 + 0] + bp[j4 * 4 + 0];
                o.y = (xs[j4 * 4 + 1] - mean) * rstd * gp[j4 * 4 + 1] + bp[j4 * 4 + 1];
                o.z = (xs[j4 * 4 + 2] - mean) * rstd * gp[j4 * 4 + 2] + bp[j4 * 4 + 2];
                o.w = (xs[j4 * 4 + 3] - mean) * rstd * gp[j4 * 4 + 3] + bp[j4 * 4 + 3];
                *(float4*)(op + j4 * 4) = o;
            }
        }
    }
}

extern "C" void kernel_launch(void* const* d_in, const int* in_sizes, int n_in,
                              void* d_out, int out_size, void* d_ws, size_t ws_size,
                              hipStream_t stream) {
    const float* h_V         = (const float*)d_in[0];
    const float* h_E         = (const float*)d_in[1];
    const int*   E_idx       = (const int*)  d_in[2];
    const float* mask_V      = (const float*)d_in[3];
    const float* mask_attend = (const float*)d_in[4];
    const float* W1_w  = (const float*)d_in[5];
    const float* W1_b  = (const float*)d_in[6];
    const float* W2_w  = (const float*)d_in[7];
    const float* W2_b  = (const float*)d_in[8];
    const float* W3_w  = (const float*)d_in[9];
    const float* W3_b  = (const float*)d_in[10];
    const float* W11_w = (const float*)d_in[11];
    const float* W11_b = (const float*)d_in[12];
    const float* W12_w = (const float*)d_in[13];
    const float* W12_b = (const float*)d_in[14];
    const float* W13_w = (const float*)d_in[15];
    const float* W13_b = (const float*)d_in[16];
    const float* Win_w  = (const float*)d_in[17];
    const float* Win_b  = (const float*)d_in[18];
    const float* Wout_w = (const float*)d_in[19];
    const float* Wout_b = (const float*)d_in[20];
    const float* g1 = (const float*)d_in[21];
    const float* b1 = (const float*)d_in[22];
    const float* g2 = (const float*)d_in[23];
    const float* b2 = (const float*)d_in[24];
    const float* g3 = (const float*)d_in[25];
    const float* b3 = (const float*)d_in[26];

    float* out    = (float*)d_out;
    float* hV_out = out;                          // [B,N,H]
    float* hE_out = out + (size_t)4 * 2048 * 128; // [B,N,K,E]
    unsigned short* wsbf = (unsigned short*)d_ws;
    float* wsf = (float*)(wsbf + W_TOTAL);
    unsigned short* zbf = (unsigned short*)wsf;   // [8192,128] bf16
    float* zm = wsf + WS_ZM;                      // [8192] fp32
    float* sS = wsf + WS_SS;   // s1 self, then (after B) s11 self
    float* sN = wsf + WS_SN;   // s1 nbr,  then (after B) s11 nbr

    prep_weights<<<(W_TOTAL + 255) / 256, 256, 0, stream>>>(
        W1_w, W2_w, W3_w, W11_w, W12_w, W13_w, Win_w, Wout_w, wsbf);

    self_gemm<<<256, 256, 0, stream>>>(h_V, wsbf, sS, sN);

    node_msg_mfma<<<4096, 512, 0, stream>>>(
        h_E, E_idx, mask_attend, wsbf, sS, sN, W1_b, W2_b, zbf, zm);

    node_fin_ffn<<<256, 256, 0, stream>>>(
        zbf, zm, h_V, mask_V, wsbf, W3_b, Win_b, Wout_b,
        g1, b1, g2, b2, hV_out, sS, sN);

    edge_update_mfma<<<4096, 512, 0, stream>>>(
        h_E, E_idx, wsbf, sS, sN,
        W11_b, W12_b, W13_b, g3, b3, hE_out);
}

// Round 7
// 473.134 us; speedup vs baseline: 1.0385x; 1.0385x over previous
//
#include <hip/hip_runtime.h>
#include <math.h>

// Problem constants
#define Kn    30
#define Hn    128
#define NB    2048          // nodes per batch
#define YS    136           // row stride (128 + 8 pad): 17 16B-groups (odd) -> conflict-free b128

// ws layout: bf16 weights, then fp32 scratch
#define OFF_W1    0
#define OFF_W2    49152
#define OFF_W3    65536
#define OFF_W11   81920
#define OFF_W12   131072
#define OFF_W13   147456
#define OFF_WIN   163840
#define OFF_WOUT  229376
#define W_TOTAL   294912
// fp32 scratch offsets (in floats, relative to end of weight region)
#define WS_ZM     524288    // zm [8192] fp32 (z bf16 occupies [0,524288) floats)
#define WS_SS     1048576   // self-term: s1self, then (aliased) s11self
#define WS_SN     2097152   // nbr-term:  s1nbr,  then (aliased) s11nbr

typedef __attribute__((ext_vector_type(8)))  short bh8;
typedef __attribute__((ext_vector_type(4)))  short bh4;
typedef __attribute__((ext_vector_type(16))) float fx16;

__device__ __forceinline__ unsigned short f2bf(float f) {
    unsigned int u = __float_as_uint(f);
    u += 0x7fffu + ((u >> 16) & 1u);        // RNE
    return (unsigned short)(u >> 16);
}
__device__ __forceinline__ float bf2f(unsigned short h) {
    return __uint_as_float(((unsigned int)h) << 16);
}
// tanh-form GELU, exp2-folded + fast rcp (vetted in R6: absmax unchanged)
__device__ __forceinline__ float gelu_f(float x) {
    float x2 = x * x;
    float p  = fmaf(x2, -0.10294415f, -2.30218409f);
    float e  = exp2f(x * p);
    return x * __builtin_amdgcn_rcpf(1.0f + e);
}
__device__ __forceinline__ fx16 mfma_bf16(bh8 a, bh8 b, fx16 c) {
    return __builtin_amdgcn_mfma_f32_32x32x16_bf16(a, b, c, 0, 0, 0);
}
__device__ __forceinline__ void st_bf4(unsigned short* dst, float4 v) {
    bh4 t;
    t.x = (short)f2bf(v.x); t.y = (short)f2bf(v.y);
    t.z = (short)f2bf(v.z); t.w = (short)f2bf(v.w);
    *(bh4*)dst = t;                          // ds_write_b64
}

// Fully-unrolled K-loop, single B n-tile.
template<int KS>
__device__ __forceinline__ void gemm_one(const unsigned short* __restrict__ aBase,
                                         const unsigned short* __restrict__ b0,
                                         fx16& acc0) {
    #pragma unroll
    for (int ks = 0; ks < KS; ks++) {
        bh8 a = *(const bh8*)(aBase + ks * 16);
        acc0 = mfma_bf16(a, *(const bh8*)(b0 + ks * 16), acc0);
    }
}

// C-layout (verified m74/m101): col = lane&31, row = (reg&3)+8*(reg>>2)+4*(lane>>5)
// G=1 epilogue: single node -> self-term loop-invariant; nbr gathered per row.
__device__ __forceinline__ void epi1_gelu_sg(const fx16& ac, int col,
                                             float bias, const float* __restrict__ sSelf,
                                             const float* __restrict__ nbrCol,
                                             const int* __restrict__ sIdx,
                                             unsigned short* __restrict__ dst, int lane) {
    int ro = 4 * (lane >> 5);
    float st = sSelf[col] + bias;
    #pragma unroll
    for (int r = 0; r < 16; r++) {
        int row = ro + (r & 3) + 8 * (r >> 2);
        float pn = nbrCol[(size_t)sIdx[row] * Hn];
        dst[row * YS + col] = f2bf(gelu_f(ac[r] + st + pn));
    }
}
__device__ __forceinline__ void epi1_gelu(const fx16& ac, int col,
                                          float bias, unsigned short* __restrict__ dst,
                                          int lane) {
    int ro = 4 * (lane >> 5);
    #pragma unroll
    for (int r = 0; r < 16; r++) {
        int row = ro + (r & 3) + 8 * (r >> 2);
        dst[row * YS + col] = f2bf(gelu_f(ac[r] + bias));
    }
}
__device__ __forceinline__ void epi1_plain(const fx16& ac, int col,
                                           float bias, unsigned short* __restrict__ dst,
                                           int lane) {
    int ro = 4 * (lane >> 5);
    #pragma unroll
    for (int r = 0; r < 16; r++) {
        int row = ro + (r & 3) + 8 * (r >> 2);
        dst[row * YS + col] = f2bf(ac[r] + bias);
    }
}

// ---------------------------------------------------------------------------
// prep: fp32 -> bf16 weights into workspace
// ---------------------------------------------------------------------------
__global__ __launch_bounds__(256) void prep_weights(
    const float* __restrict__ W1, const float* __restrict__ W2,
    const float* __restrict__ W3, const float* __restrict__ W11,
    const float* __restrict__ W12, const float* __restrict__ W13,
    const float* __restrict__ Win, const float* __restrict__ Wout,
    unsigned short* __restrict__ wsbf) {
    int i = blockIdx.x * 256 + threadIdx.x;
    if (i >= W_TOTAL) return;
    float v;
    if      (i < OFF_W2)   v = W1[i - OFF_W1];
    else if (i < OFF_W3)   v = W2[i - OFF_W2];
    else if (i < OFF_W11)  v = W3[i - OFF_W3];
    else if (i < OFF_W12)  v = W11[i - OFF_W11];
    else if (i < OFF_W13)  v = W12[i - OFF_W12];
    else if (i < OFF_WIN)  v = W13[i - OFF_W13];
    else if (i < OFF_WOUT) v = Win[i - OFF_WIN];
    else                   v = Wout[i - OFF_WOUT];
    wsbf[i] = f2bf(v);
}

// ---------------------------------------------------------------------------
// self+nbr terms for node GEMM1:
//   s1s[p] = h_V[p] @ W1[:,0:128]^T      (self columns)
//   s1n[p] = h_V[p] @ W1[:,256:384]^T    (neighbor columns; gathered later)
// ---------------------------------------------------------------------------
__global__ __launch_bounds__(256) void self_gemm(
    const float* __restrict__ hv, const unsigned short* __restrict__ wsbf,
    float* __restrict__ s1s, float* __restrict__ s1n) {
    __shared__ __align__(16) unsigned short sA[32 * YS];
    const int tid = threadIdx.x;
    const int p0 = blockIdx.x * 32;
    const unsigned short* W1bf = wsbf + OFF_W1;
    for (int i = tid; i < 1024; i += 256) {
        int r = i >> 5, c4 = (i & 31) << 2;
        float4 v = *(const float4*)(hv + (size_t)(p0 + r) * Hn + c4);
        st_bf4(sA + r * YS + c4, v);
    }
    __syncthreads();
    const int wid = tid >> 6, lane = tid & 63;
    const int lane31 = lane & 31, lk = (lane >> 5) << 3;
    fx16 accS = {}, accN = {};
    const unsigned short* a   = sA + lane31 * YS + lk;
    const unsigned short* bwS = W1bf + (size_t)(32 * wid + lane31) * 384 + lk;        // cols 0..127
    const unsigned short* bwN = bwS + 256;                                            // cols 256..383
    #pragma unroll
    for (int ks = 0; ks < 8; ks++) {
        bh8 av = *(const bh8*)(a + ks * 16);
        accS = mfma_bf16(av, *(const bh8*)(bwS + ks * 16), accS);
        accN = mfma_bf16(av, *(const bh8*)(bwN + ks * 16), accN);
    }
    int col = 32 * wid + lane31;
    #pragma unroll
    for (int r = 0; r < 16; r++) {
        int row = (r & 3) + 8 * (r >> 2) + 4 * (lane >> 5);
        s1s[(size_t)(p0 + row) * Hn + col] = accS[r];
        s1n[(size_t)(p0 + row) * Hn + col] = accN[r];
    }
}

// ---------------------------------------------------------------------------
// Kernel A: node message MLP, G=1 node/block (256 thr, 4 waves; each wave
// one 32x32 tile covering ALL 30 edges of the node for its col-quarter).
// k-reduction is wave-local -> z written directly, 2 barriers total.
// LDS ~17.8 KB -> 8 blocks/CU (32 waves/CU).
// ---------------------------------------------------------------------------
__global__ __launch_bounds__(256, 8) void node_msg_mfma(
    const float* __restrict__ h_E, const int* __restrict__ E_idx,
    const float* __restrict__ mask_attend,
    const unsigned short* __restrict__ wsbf,
    const float* __restrict__ s1s, const float* __restrict__ s1n,
    const float* __restrict__ W1_b, const float* __restrict__ W2_b,
    unsigned short* __restrict__ zbf, float* __restrict__ zm) {
    __shared__ __align__(16) unsigned short sX[32 * YS]; // h_E (32 rows: 30 + 2 pad)
    __shared__ __align__(16) unsigned short sY[32 * YS];
    __shared__ float sS1[128];
    __shared__ float sMask[32];
    __shared__ int   sIdx[32];

    const int tid = threadIdx.x;
    const int p = blockIdx.x;
    const int bB = p >> 11;
    const unsigned short* W1bf = wsbf + OFF_W1;
    const unsigned short* W2bf = wsbf + OFF_W2;

    // ---- staging: h_E rows 0..29 ----
    for (int i = tid; i < 960; i += 256) {
        int r = i >> 5, c4 = (i & 31) << 2;
        float4 v = *(const float4*)(h_E + ((size_t)p * Kn + r) * Hn + c4);
        st_bf4(sX + r * YS + c4, v);
    }
    if (tid < 136)                                   // zero pad rows 30..31
        ((unsigned int*)(sX + 30 * YS))[tid] = 0;
    if (tid < 32) {
        int c4 = tid << 2;
        *(float4*)(sS1 + c4) = *(const float4*)(s1s + (size_t)p * Hn + c4);
    }
    if (tid < 32) {
        sMask[tid] = (tid < Kn) ? mask_attend[p * Kn + tid] : 0.f;
        sIdx[tid]  = (tid < Kn) ? E_idx[p * Kn + tid] : 0;
    }
    __syncthreads();

    const int wid = tid >> 6, lane = tid & 63;
    const int lane31 = lane & 31, lk = (lane >> 5) << 3;
    const fx16 zv = {};
    const int col = 32 * wid + lane31;

    // ---- GEMM1: X[32,128] @ W1[:,128:256]^T + s1s + s1n(gathered) + b -> GELU -> Y ----
    fx16 acc = zv;
    gemm_one<8>(sX + lane31 * YS + lk,
                W1bf + (size_t)col * 384 + 128 + lk, acc);
    epi1_gelu_sg(acc, col, W1_b[col], sS1,
                 s1n + (size_t)bB * NB * Hn + col, sIdx, sY, lane);
    __syncthreads();

    // ---- GEMM2 + fused gelu + masked k-reduction -> z (wave-local) ----
    acc = zv;
    gemm_one<8>(sY + lane31 * YS + lk,
                W2bf + (size_t)col * 128 + lk, acc);
    {
        float bias = W2_b[col];
        float sum = 0.f;
        #pragma unroll
        for (int r = 0; r < 16; r++) {
            int row = (r & 3) + 8 * (r >> 2) + 4 * (lane >> 5);
            if (row < Kn) sum += gelu_f(acc[r] + bias) * sMask[row];
        }
        sum += __shfl_down(sum, 32);
        if (lane < 32)
            zbf[(size_t)p * Hn + col] = f2bf(sum * (1.0f / 30.0f));
    }
    if (tid == 0) {
        float s = 0.f;
        #pragma unroll
        for (int k = 0; k < Kn; k++) s += sMask[k];
        zm[p] = s * (1.0f / 30.0f);
    }
}

// ---------------------------------------------------------------------------
// Kernel B: dh = z@W3^T + zm*b3; LN1 (+h_V residual); FFN; LN2 + mask_V;
// then s11s/s11n = hV_out @ W11{self,nbr}^T. hmid never touches HBM.
// ---------------------------------------------------------------------------
__global__ __launch_bounds__(256) void node_fin_ffn(
    const unsigned short* __restrict__ zbf, const float* __restrict__ zm,
    const float* __restrict__ h_V, const float* __restrict__ mask_V,
    const unsigned short* __restrict__ wsbf,
    const float* __restrict__ W3_b, const float* __restrict__ Win_b,
    const float* __restrict__ Wout_b,
    const float* __restrict__ g1v, const float* __restrict__ b1v,
    const float* __restrict__ g2v, const float* __restrict__ b2v,
    float* __restrict__ hV_out, float* __restrict__ s11s, float* __restrict__ s11n) {
    __shared__ __align__(16) unsigned short sA[32 * YS];  // z bf16, then hmid bf16
    __shared__ __align__(16) unsigned short sH[32 * YS];  // hidden chunk bf16
    __shared__ __align__(16) float sO[32 * 132];          // dh fp32, then FFN-out fp32
    __shared__ __align__(16) float sM[32 * 132];          // hmid fp32
    __shared__ __align__(16) unsigned short sV[32 * YS];  // hV_out bf16 for s11
    __shared__ float sZm[32];

    const int tid = threadIdx.x;
    const int p0 = blockIdx.x * 32;
    const unsigned short* W3bf   = wsbf + OFF_W3;
    const unsigned short* Winbf  = wsbf + OFF_WIN;
    const unsigned short* Woutbf = wsbf + OFF_WOUT;
    const unsigned short* W11bf  = wsbf + OFF_W11;

    for (int i = tid; i < 512; i += 256) {
        int r = i >> 4, c8 = (i & 15) << 3;
        *(bh8*)(sA + r * YS + c8) = *(const bh8*)(zbf + (size_t)(p0 + r) * Hn + c8);
    }
    if (tid < 32) sZm[tid] = zm[p0 + tid];
    __syncthreads();

    const int wid = tid >> 6, lane = tid & 63;
    const int lane31 = lane & 31, lk = (lane >> 5) << 3;
    const fx16 zv = {};

    // ---- dh GEMM: z[32,128] @ W3^T ----
    {
        fx16 acc = zv;
        const unsigned short* a  = sA + lane31 * YS + lk;
        const unsigned short* bw = W3bf + (size_t)(32 * wid + lane31) * 128 + lk;
        #pragma unroll
        for (int ks = 0; ks < 8; ks++)
            acc = mfma_bf16(*(const bh8*)(a + ks * 16), *(const bh8*)(bw + ks * 16), acc);
        int col = 32 * wid + lane31;
        float bias = W3_b[col];
        #pragma unroll
        for (int r = 0; r < 16; r++) {
            int row = (r & 3) + 8 * (r >> 2) + 4 * (lane >> 5);
            sO[row * 132 + col] = acc[r] + sZm[row] * bias;
        }
    }
    __syncthreads();

    // ---- LN1: x = h_V + dh -> hmid (sM fp32 + sA bf16) ----
    for (int r = wid; r < 32; r += 4) {
        float x0 = sO[r * 132 + lane]      + h_V[(size_t)(p0 + r) * Hn + lane];
        float x1 = sO[r * 132 + 64 + lane] + h_V[(size_t)(p0 + r) * Hn + 64 + lane];
        float s = x0 + x1, q = x0 * x0 + x1 * x1;
        #pragma unroll
        for (int off = 32; off; off >>= 1) { s += __shfl_down(s, off); q += __shfl_down(q, off); }
        s = __shfl(s, 0); q = __shfl(q, 0);
        float mean = s * 0.0078125f;
        float rstd = rsqrtf(q * 0.0078125f - mean * mean + 1e-5f);
        float m0 = (x0 - mean) * rstd * g1v[lane]      + b1v[lane];
        float m1 = (x1 - mean) * rstd * g1v[lane + 64] + b1v[lane + 64];
        sM[r * 132 + lane]      = m0;
        sM[r * 132 + 64 + lane] = m1;
        sA[r * YS + lane]      = f2bf(m0);
        sA[r * YS + 64 + lane] = f2bf(m1);
    }
    __syncthreads();

    // ---- FFN ----
    fx16 accO = zv;
    for (int c = 0; c < 4; c++) {
        int hcol = 128 * c + 32 * wid + lane31;
        fx16 t = zv;
        {
            const unsigned short* a  = sA + lane31 * YS + lk;
            const unsigned short* bw = Winbf + (size_t)hcol * 128 + lk;
            #pragma unroll
            for (int ks = 0; ks < 8; ks++)
                t = mfma_bf16(*(const bh8*)(a + ks * 16), *(const bh8*)(bw + ks * 16), t);
        }
        float bias = Win_b[hcol];
        int colL = 32 * wid + lane31;
        #pragma unroll
        for (int r = 0; r < 16; r++) {
            int row = (r & 3) + 8 * (r >> 2) + 4 * (lane >> 5);
            sH[row * YS + colL] = f2bf(gelu_f(t[r] + bias));
        }
        __syncthreads();
        {
            const unsigned short* a  = sH + lane31 * YS + lk;
            const unsigned short* bw = Woutbf + (size_t)(32 * wid + lane31) * 512 + 128 * c + lk;
            #pragma unroll
            for (int ks = 0; ks < 8; ks++)
                accO = mfma_bf16(*(const bh8*)(a + ks * 16), *(const bh8*)(bw + ks * 16), accO);
        }
        __syncthreads();
    }
    {
        int col = 32 * wid + lane31;
        float bias = Wout_b[col];
        #pragma unroll
        for (int r = 0; r < 16; r++) {
            int row = (r & 3) + 8 * (r >> 2) + 4 * (lane >> 5);
            sO[row * 132 + col] = accO[r] + bias;
        }
    }
    __syncthreads();

    // ---- LN2 + mask_V -> hV_out, sV ----
    for (int r = wid; r < 32; r += 4) {
        float x0 = sO[r * 132 + lane]      + sM[r * 132 + lane];
        float x1 = sO[r * 132 + 64 + lane] + sM[r * 132 + 64 + lane];
        float s = x0 + x1, q = x0 * x0 + x1 * x1;
        #pragma unroll
        for (int off = 32; off; off >>= 1) { s += __shfl_down(s, off); q += __shfl_down(q, off); }
        s = __shfl(s, 0); q = __shfl(q, 0);
        float mean = s * 0.0078125f;
        float rstd = rsqrtf(q * 0.0078125f - mean * mean + 1e-5f);
        float mv = mask_V[p0 + r];
        float y0 = ((x0 - mean) * rstd * g2v[lane]      + b2v[lane])      * mv;
        float y1 = ((x1 - mean) * rstd * g2v[lane + 64] + b2v[lane + 64]) * mv;
        hV_out[(size_t)(p0 + r) * Hn + lane]      = y0;
        hV_out[(size_t)(p0 + r) * Hn + 64 + lane] = y1;
        sV[r * YS + lane]      = f2bf(y0);
        sV[r * YS + 64 + lane] = f2bf(y1);
    }
    __syncthreads();

    // ---- s11s/s11n = hV_out @ W11{self,nbr}^T ----
    {
        int col = 32 * wid + lane31;
        fx16 accS = zv, accN = zv;
        const unsigned short* a   = sV + lane31 * YS + lk;
        const unsigned short* bwS = W11bf + (size_t)col * 384 + lk;        // self cols 0..127
        const unsigned short* bwN = W11bf + (size_t)col * 384 + 256 + lk;  // nbr  cols 256..383
        #pragma unroll
        for (int ks = 0; ks < 8; ks++) {
            bh8 av = *(const bh8*)(a + ks * 16);
            accS = mfma_bf16(av, *(const bh8*)(bwS + ks * 16), accS);
            accN = mfma_bf16(av, *(const bh8*)(bwN + ks * 16), accN);
        }
        #pragma unroll
        for (int r = 0; r < 16; r++) {
            int row = (r & 3) + 8 * (r >> 2) + 4 * (lane >> 5);
            s11s[(size_t)(p0 + row) * Hn + col] = accS[r];
            s11n[(size_t)(p0 + row) * Hn + col] = accN[r];
        }
    }
}

// ---------------------------------------------------------------------------
// Kernel C: edge update, G=1 node/block (256 thr, 4 waves). R5-verified
// barrier structure (gemm -> sync -> epi -> sync, in-place sY); serial LN
// tail over 4 waves; sX (h_E) live to the end for the residual.
// LDS ~17.6 KB -> 8 blocks/CU.
// ---------------------------------------------------------------------------
__global__ __launch_bounds__(256, 8) void edge_update_mfma(
    const float* __restrict__ h_E, const int* __restrict__ E_idx,
    const unsigned short* __restrict__ wsbf,
    const float* __restrict__ s11s, const float* __restrict__ s11n,
    const float* __restrict__ W11_b, const float* __restrict__ W12_b,
    const float* __restrict__ W13_b,
    const float* __restrict__ g3v, const float* __restrict__ b3v,
    float* __restrict__ hE_out) {
    __shared__ __align__(16) unsigned short sX[32 * YS]; // h_E, live to end (residual)
    __shared__ __align__(16) unsigned short sY[32 * YS];
    __shared__ float sS11[128];
    __shared__ int   sIdx[32];

    const int tid = threadIdx.x;
    const int p = blockIdx.x;
    const int bB = p >> 11;
    const unsigned short* W11bf = wsbf + OFF_W11;
    const unsigned short* W12bf = wsbf + OFF_W12;
    const unsigned short* W13bf = wsbf + OFF_W13;

    for (int i = tid; i < 960; i += 256) {
        int r = i >> 5, c4 = (i & 31) << 2;
        float4 v = *(const float4*)(h_E + ((size_t)p * Kn + r) * Hn + c4);
        st_bf4(sX + r * YS + c4, v);
    }
    if (tid < 136)
        ((unsigned int*)(sX + 30 * YS))[tid] = 0;
    if (tid < 32) {
        int c4 = tid << 2;
        *(float4*)(sS11 + c4) = *(const float4*)(s11s + (size_t)p * Hn + c4);
    }
    if (tid < 32) sIdx[tid] = (tid < Kn) ? E_idx[p * Kn + tid] : 0;
    __syncthreads();

    const int wid = tid >> 6, lane = tid & 63;
    const int lane31 = lane & 31, lk = (lane >> 5) << 3;
    const fx16 zv = {};
    const int col = 32 * wid + lane31;

    fx16 acc = zv;
    gemm_one<8>(sX + lane31 * YS + lk,
                W11bf + (size_t)col * 384 + 128 + lk, acc);
    epi1_gelu_sg(acc, col, W11_b[col], sS11,
                 s11n + (size_t)bB * NB * Hn + col, sIdx, sY, lane);
    __syncthreads();

    acc = zv;
    gemm_one<8>(sY + lane31 * YS + lk,
                W12bf + (size_t)col * 128 + lk, acc);
    __syncthreads();
    epi1_gelu(acc, col, W12_b[col], sY, lane);
    __syncthreads();

    acc = zv;
    gemm_one<8>(sY + lane31 * YS + lk,
                W13bf + (size_t)col * 128 + lk, acc);
    __syncthreads();
    epi1_plain(acc, col, W13_b[col], sY, lane);
    __syncthreads();

    // per-edge-row LN over E=128 (residual from bf16 h_E in sX)
    for (int r = wid; r < Kn; r += 4) {
        float x0 = bf2f(sX[r * YS + lane])      + bf2f(sY[r * YS + lane]);
        float x1 = bf2f(sX[r * YS + 64 + lane]) + bf2f(sY[r * YS + 64 + lane]);
        float s = x0 + x1, q = x0 * x0 + x1 * x1;
        #pragma unroll
        for (int off = 32; off; off >>= 1) { s += __shfl_down(s, off); q += __shfl_down(q, off); }
        s = __shfl(s, 0); q = __shfl(q, 0);
        float mean = s * 0.0078125f;
        float rstd = rsqrtf(q * 0.0078125f - mean * mean + 1e-5f);
        float* op = hE_out + ((size_t)p * Kn + r) * Hn;
        op[lane]      = (x0 - mean) * rstd * g3v[lane]      + b3v[lane];
        op[lane + 64] = (x1 - mean) * rstd * g3v[lane + 64] + b3v[lane + 64];
    }
}

extern "C" void kernel_launch(void* const* d_in, const int* in_sizes, int n_in,
                              void* d_out, int out_size, void* d_ws, size_t ws_size,
                              hipStream_t stream) {
    const float* h_V         = (const float*)d_in[0];
    const float* h_E         = (const float*)d_in[1];
    const int*   E_idx       = (const int*)  d_in[2];
    const float* mask_V      = (const float*)d_in[3];
    const float* mask_attend = (const float*)d_in[4];
    const float* W1_w  = (const float*)d_in[5];
    const float* W1_b  = (const float*)d_in[6];
    const float* W2_w  = (const float*)d_in[7];
    const float* W2_b  = (const float*)d_in[8];
    const float* W3_w  = (const float*)d_in[9];
    const float* W3_b  = (const float*)d_in[10];
    const float* W11_w = (const float*)d_in[11];
    const float* W11_b = (const float*)d_in[12];
    const float* W12_w = (const float*)d_in[13];
    const float* W12_b = (const float*)d_in[14];
    const float* W13_w = (const float*)d_in[15];
    const float* W13_b = (const float*)d_in[16];
    const float* Win_w  = (const float*)d_in[17];
    const float* Win_b  = (const float*)d_in[18];
    const float* Wout_w = (const float*)d_in[19];
    const float* Wout_b = (const float*)d_in[20];
    const float* g1 = (const float*)d_in[21];
    const float* b1 = (const float*)d_in[22];
    const float* g2 = (const float*)d_in[23];
    const float* b2 = (const float*)d_in[24];
    const float* g3 = (const float*)d_in[25];
    const float* b3 = (const float*)d_in[26];

    float* out    = (float*)d_out;
    float* hV_out = out;                          // [B,N,H]
    float* hE_out = out + (size_t)4 * 2048 * 128; // [B,N,K,E]
    unsigned short* wsbf = (unsigned short*)d_ws;
    float* wsf = (float*)(wsbf + W_TOTAL);
    unsigned short* zbf = (unsigned short*)wsf;   // [8192,128] bf16
    float* zm = wsf + WS_ZM;                      // [8192] fp32
    float* sS = wsf + WS_SS;   // s1 self, then (after B) s11 self
    float* sN = wsf + WS_SN;   // s1 nbr,  then (after B) s11 nbr

    prep_weights<<<(W_TOTAL + 255) / 256, 256, 0, stream>>>(
        W1_w, W2_w, W3_w, W11_w, W12_w, W13_w, Win_w, Wout_w, wsbf);

    self_gemm<<<256, 256, 0, stream>>>(h_V, wsbf, sS, sN);

    node_msg_mfma<<<8192, 256, 0, stream>>>(
        h_E, E_idx, mask_attend, wsbf, sS, sN, W1_b, W2_b, zbf, zm);

    node_fin_ffn<<<256, 256, 0, stream>>>(
        zbf, zm, h_V, mask_V, wsbf, W3_b, Win_b, Wout_b,
        g1, b1, g2, b2, hV_out, sS, sN);

    edge_update_mfma<<<8192, 256, 0, stream>>>(
        h_E, E_idx, wsbf, sS, sN,
        W11_b, W12_b, W13_b, g3, b3, hE_out);
}